// Round 1
// baseline (4514.338 us; speedup 1.0000x reference)
//
#include <hip/hip_runtime.h>

#define D 128

// ---------------------------------------------------------------------------
// Phase 1: edge scatter.  threads t: e = t>>5 (edge), c = t&31 (float4 chunk).
// Half-wave (32 lanes x float4) reads one full 512B source row coalesced,
// then atomically accumulates into agg[dst].  Lane c==0 bumps the edge count.
// ---------------------------------------------------------------------------
__global__ __launch_bounds__(256) void scatter_add_kernel(
    const float* __restrict__ x_src,
    const int* __restrict__ src,
    const int* __restrict__ dst,
    float* __restrict__ agg,
    float* __restrict__ cnt,
    int E)
{
    long long t = (long long)blockIdx.x * blockDim.x + threadIdx.x;
    int e = (int)(t >> 5);
    int c = (int)(t & 31);
    if (e >= E) return;
    int s = src[e];
    int d = dst[e];
    const float4 v = *reinterpret_cast<const float4*>(x_src + (long long)s * D + c * 4);
    float* a = agg + (long long)d * D + c * 4;
    atomicAdd(a + 0, v.x);
    atomicAdd(a + 1, v.y);
    atomicAdd(a + 2, v.z);
    atomicAdd(a + 3, v.w);
    if (c == 0) atomicAdd(cnt + d, 1.0f);
}

// ---------------------------------------------------------------------------
// Phase 2: out[i][j] = relu( sum_rel( mean_rel[i]·Wl_rel[j] + bl_rel[j]
//                                     + x_dst[i]·Wr_rel[j] ) )
// Block = 128 threads (one per output column j), ROWS=8 dst rows per block.
// mean/x rows staged in LDS (broadcast reads); W rows read from L2 per-thread.
// ---------------------------------------------------------------------------
template<bool HAS_B>
__global__ __launch_bounds__(128) void sage_out_kernel(
    const float* __restrict__ agg_a, const float* __restrict__ cnt_a,
    const float* __restrict__ Wl_a, const float* __restrict__ bl_a,
    const float* __restrict__ Wr_a,
    const float* __restrict__ agg_b, const float* __restrict__ cnt_b,
    const float* __restrict__ Wl_b, const float* __restrict__ bl_b,
    const float* __restrict__ Wr_b,
    const float* __restrict__ x_dst,
    float* __restrict__ out,
    int n_dst)
{
    constexpr int ROWS = 8;
    __shared__ float s_ma[ROWS][D];
    __shared__ float s_x [ROWS][D];
    __shared__ float s_mb[HAS_B ? ROWS : 1][D];

    const int j = threadIdx.x;
    const int row0 = blockIdx.x * ROWS;

    for (int r = 0; r < ROWS; ++r) {
        int i = row0 + r;
        if (i < n_dst) {
            float ca = fmaxf(cnt_a[i], 1.0f);
            s_ma[r][j] = agg_a[(long long)i * D + j] * (1.0f / ca);
            s_x [r][j] = x_dst[(long long)i * D + j];
            if constexpr (HAS_B) {
                float cb = fmaxf(cnt_b[i], 1.0f);
                s_mb[r][j] = agg_b[(long long)i * D + j] * (1.0f / cb);
            }
        } else {
            s_ma[r][j] = 0.f;
            s_x [r][j] = 0.f;
            if constexpr (HAS_B) s_mb[r][j] = 0.f;
        }
    }
    __syncthreads();

    float bias = bl_a[j];
    if constexpr (HAS_B) bias += bl_b[j];

    float acc[ROWS];
    #pragma unroll
    for (int r = 0; r < ROWS; ++r) acc[r] = bias;

    for (int k = 0; k < D; k += 4) {
        const float4 wla = *reinterpret_cast<const float4*>(Wl_a + (long long)j * D + k);
        const float4 wra = *reinterpret_cast<const float4*>(Wr_a + (long long)j * D + k);
        float4 wlb = {0,0,0,0}, wrb = {0,0,0,0};
        if constexpr (HAS_B) {
            wlb = *reinterpret_cast<const float4*>(Wl_b + (long long)j * D + k);
            wrb = *reinterpret_cast<const float4*>(Wr_b + (long long)j * D + k);
        }
        #pragma unroll
        for (int r = 0; r < ROWS; ++r) {
            const float4 ma = *reinterpret_cast<const float4*>(&s_ma[r][k]);
            const float4 xr = *reinterpret_cast<const float4*>(&s_x [r][k]);
            float a = acc[r];
            a += ma.x * wla.x + ma.y * wla.y + ma.z * wla.z + ma.w * wla.w;
            a += xr.x * wra.x + xr.y * wra.y + xr.z * wra.z + xr.w * wra.w;
            if constexpr (HAS_B) {
                const float4 mb = *reinterpret_cast<const float4*>(&s_mb[r][k]);
                a += mb.x * wlb.x + mb.y * wlb.y + mb.z * wlb.z + mb.w * wlb.w;
                a += xr.x * wrb.x + xr.y * wrb.y + xr.z * wrb.z + xr.w * wrb.w;
            }
            acc[r] = a;
        }
    }

    for (int r = 0; r < ROWS; ++r) {
        int i = row0 + r;
        if (i < n_dst) out[(long long)i * D + j] = fmaxf(acc[r], 0.f);
    }
}

extern "C" void kernel_launch(void* const* d_in, const int* in_sizes, int n_in,
                              void* d_out, int out_size, void* d_ws, size_t ws_size,
                              hipStream_t stream) {
    const float* x_job = (const float*)d_in[0];
    const float* x_st  = (const float*)d_in[1];
    const float* x_mc  = (const float*)d_in[2];
    const float* x_rb  = (const float*)d_in[3];

    const int N_ST = 10000, N_MC = 10000, N_RB = 5000, E = 500000;

    struct Rel { const int* src; const int* dst; const float* Wl; const float* bl; const float* Wr; };
    Rel rel[5];
    for (int r = 0; r < 5; ++r) {
        rel[r].src = (const int*)  d_in[4 + r * 5 + 0];
        rel[r].dst = (const int*)  d_in[4 + r * 5 + 1];
        rel[r].Wl  = (const float*)d_in[4 + r * 5 + 2];
        rel[r].bl  = (const float*)d_in[4 + r * 5 + 3];
        rel[r].Wr  = (const float*)d_in[4 + r * 5 + 4];
    }
    const int ndst[5] = {N_ST, N_ST, N_MC, N_MC, N_RB};

    // workspace layout: 5 agg arrays, then 5 cnt arrays (23.2 MB total)
    float* ws = (float*)d_ws;
    float* agg[5]; float* cnt[5];
    size_t off = 0;
    for (int r = 0; r < 5; ++r) { agg[r] = ws + off; off += (size_t)ndst[r] * D; }
    for (int r = 0; r < 5; ++r) { cnt[r] = ws + off; off += (size_t)ndst[r]; }
    hipMemsetAsync(d_ws, 0, off * sizeof(float), stream);

    const long long threads = (long long)E * 32;
    const int blocks = (int)((threads + 255) / 256);
    for (int r = 0; r < 5; ++r) {
        scatter_add_kernel<<<blocks, 256, 0, stream>>>(
            x_job, rel[r].src, rel[r].dst, agg[r], cnt[r], E);
    }

    float* out = (float*)d_out;
    sage_out_kernel<true><<<(N_ST + 7) / 8, 128, 0, stream>>>(
        agg[0], cnt[0], rel[0].Wl, rel[0].bl, rel[0].Wr,
        agg[1], cnt[1], rel[1].Wl, rel[1].bl, rel[1].Wr,
        x_st, out, N_ST);
    sage_out_kernel<true><<<(N_MC + 7) / 8, 128, 0, stream>>>(
        agg[2], cnt[2], rel[2].Wl, rel[2].bl, rel[2].Wr,
        agg[3], cnt[3], rel[3].Wl, rel[3].bl, rel[3].Wr,
        x_mc, out + (size_t)N_ST * D, N_MC);
    sage_out_kernel<false><<<(N_RB + 7) / 8, 128, 0, stream>>>(
        agg[4], cnt[4], rel[4].Wl, rel[4].bl, rel[4].Wr,
        nullptr, nullptr, nullptr, nullptr, nullptr,
        x_rb, out + (size_t)(N_ST + N_MC) * D, N_RB);
}

// Round 2
// 611.480 us; speedup vs baseline: 7.3826x; 7.3826x over previous
//
#include <hip/hip_runtime.h>

#define D 128
#define NREL 5

// ---- pointer bundles passed by value (kernarg) ----
struct RelIdx {
    const int* src[NREL];
    const int* dst[NREL];
};
struct CsrPtrs {
    int* csr[NREL];   // per-rel edge source list, grouped by dst (size E)
    int* rp [NREL];   // histogram -> row_ptr (size n_dst+1)
    int* cur[NREL];   // fill cursors (size n_dst)
};
struct GatherPtrs {
    const int* csr[NREL];
    const int* rp [NREL];
    float*     mean[NREL];
};
struct ScanArgs { int n[NREL]; };

// ---------------------------------------------------------------------------
// CSR build step 1: per-dst edge count (int atomics, all 5 rels per thread)
// ---------------------------------------------------------------------------
__global__ __launch_bounds__(256) void hist_kernel(RelIdx idx, CsrPtrs p, int E) {
    int e = blockIdx.x * blockDim.x + threadIdx.x;
    if (e >= E) return;
    #pragma unroll
    for (int r = 0; r < NREL; ++r)
        atomicAdd(&p.rp[r][idx.dst[r][e]], 1);
}

// ---------------------------------------------------------------------------
// CSR build step 2: in-place exclusive scan of the histogram. One block per
// relation; thread t owns a contiguous chunk, block-scan of partial sums.
// Also seeds the fill cursors.
// ---------------------------------------------------------------------------
__global__ __launch_bounds__(256) void scan_kernel(CsrPtrs p, ScanArgs a, int E) {
    int r = blockIdx.x;
    int n = a.n[r];
    int* h = p.rp[r];
    int* c = p.cur[r];
    int tid = threadIdx.x;
    int chunk = (n + 255) >> 8;
    int lo = tid * chunk, hi = min(lo + chunk, n);
    int sum = 0;
    for (int i = lo; i < hi; ++i) sum += h[i];
    __shared__ int s[256];
    s[tid] = sum;
    __syncthreads();
    for (int d = 1; d < 256; d <<= 1) {
        int v = (tid >= d) ? s[tid - d] : 0;
        __syncthreads();
        if (tid >= d) s[tid] += v;
        __syncthreads();
    }
    int run = s[tid] - sum;              // exclusive prefix of this chunk
    for (int i = lo; i < hi; ++i) { int v = h[i]; h[i] = run; c[i] = run; run += v; }
    if (tid == 0) h[n] = E;
}

// ---------------------------------------------------------------------------
// CSR build step 3: scatter edge source ids into dst-grouped slots
// ---------------------------------------------------------------------------
__global__ __launch_bounds__(256) void fill_kernel(RelIdx idx, CsrPtrs p, int E) {
    int e = blockIdx.x * blockDim.x + threadIdx.x;
    if (e >= E) return;
    #pragma unroll
    for (int r = 0; r < NREL; ++r) {
        int d = idx.dst[r][e];
        int pos = atomicAdd(&p.cur[r][d], 1);
        p.csr[r][pos] = idx.src[r][e];
    }
}

// ---------------------------------------------------------------------------
// Gather-reduce: one 64-lane wave per dst node (4 waves/block). Each lane
// owns 2 columns (float2); per edge the wave reads one full 512B x_job row
// coalesced. No atomics; single write of the mean row at the end.
// ---------------------------------------------------------------------------
__global__ __launch_bounds__(256) void gather_mean_kernel(
    GatherPtrs g, const float* __restrict__ x_job, int total_nodes)
{
    int w = blockIdx.x * 4 + (threadIdx.x >> 6);
    int lane = threadIdx.x & 63;
    if (w >= total_nodes) return;
    int r, i;
    if      (w < 10000) { r = 0; i = w; }
    else if (w < 20000) { r = 1; i = w - 10000; }
    else if (w < 30000) { r = 2; i = w - 20000; }
    else if (w < 40000) { r = 3; i = w - 30000; }
    else                { r = 4; i = w - 40000; }
    const int* csr = g.csr[r];
    int start = g.rp[r][i], end = g.rp[r][i + 1];
    const float* base = x_job + lane * 2;
    float ax = 0.f, ay = 0.f;
    int k = start;
    for (; k + 4 <= end; k += 4) {
        int s0 = csr[k], s1 = csr[k + 1], s2 = csr[k + 2], s3 = csr[k + 3];
        float2 v0 = *reinterpret_cast<const float2*>(base + s0 * D);
        float2 v1 = *reinterpret_cast<const float2*>(base + s1 * D);
        float2 v2 = *reinterpret_cast<const float2*>(base + s2 * D);
        float2 v3 = *reinterpret_cast<const float2*>(base + s3 * D);
        ax += v0.x + v1.x + v2.x + v3.x;
        ay += v0.y + v1.y + v2.y + v3.y;
    }
    for (; k < end; ++k) {
        float2 v = *reinterpret_cast<const float2*>(base + csr[k] * D);
        ax += v.x; ay += v.y;
    }
    float inv = 1.0f / (float)max(end - start, 1);
    float2 m; m.x = ax * inv; m.y = ay * inv;
    *reinterpret_cast<float2*>(g.mean[r] + (size_t)i * D + lane * 2) = m;
}

// ---------------------------------------------------------------------------
// Epilogue: out[i][j] = relu( sum_rel( mean_rel[i]·Wl_rel[j] + bl_rel[j]
//                                      + x_dst[i]·Wr_rel[j] ) )
// mean_a may alias `out`: each block stages its own rows to LDS, syncs,
// computes, then overwrites only those rows — no cross-block hazard.
// ---------------------------------------------------------------------------
template<bool HAS_B>
__global__ __launch_bounds__(128) void sage_out_kernel(
    const float* __restrict__ mean_a,
    const float* __restrict__ Wl_a, const float* __restrict__ bl_a,
    const float* __restrict__ Wr_a,
    const float* __restrict__ mean_b,
    const float* __restrict__ Wl_b, const float* __restrict__ bl_b,
    const float* __restrict__ Wr_b,
    const float* __restrict__ x_dst,
    float* __restrict__ out,
    int n_dst)
{
    constexpr int ROWS = 8;
    __shared__ float s_ma[ROWS][D];
    __shared__ float s_x [ROWS][D];
    __shared__ float s_mb[HAS_B ? ROWS : 1][D];

    const int j = threadIdx.x;
    const int row0 = blockIdx.x * ROWS;

    for (int r = 0; r < ROWS; ++r) {
        int i = row0 + r;
        if (i < n_dst) {
            s_ma[r][j] = mean_a[(size_t)i * D + j];
            s_x [r][j] = x_dst [(size_t)i * D + j];
            if constexpr (HAS_B) s_mb[r][j] = mean_b[(size_t)i * D + j];
        } else {
            s_ma[r][j] = 0.f;
            s_x [r][j] = 0.f;
            if constexpr (HAS_B) s_mb[r][j] = 0.f;
        }
    }
    __syncthreads();

    float bias = bl_a[j];
    if constexpr (HAS_B) bias += bl_b[j];

    float acc[ROWS];
    #pragma unroll
    for (int r = 0; r < ROWS; ++r) acc[r] = bias;

    for (int k = 0; k < D; k += 4) {
        const float4 wla = *reinterpret_cast<const float4*>(Wl_a + (size_t)j * D + k);
        const float4 wra = *reinterpret_cast<const float4*>(Wr_a + (size_t)j * D + k);
        float4 wlb = {0,0,0,0}, wrb = {0,0,0,0};
        if constexpr (HAS_B) {
            wlb = *reinterpret_cast<const float4*>(Wl_b + (size_t)j * D + k);
            wrb = *reinterpret_cast<const float4*>(Wr_b + (size_t)j * D + k);
        }
        #pragma unroll
        for (int r = 0; r < ROWS; ++r) {
            const float4 ma = *reinterpret_cast<const float4*>(&s_ma[r][k]);
            const float4 xr = *reinterpret_cast<const float4*>(&s_x [r][k]);
            float a = acc[r];
            a += ma.x * wla.x + ma.y * wla.y + ma.z * wla.z + ma.w * wla.w;
            a += xr.x * wra.x + xr.y * wra.y + xr.z * wra.z + xr.w * wra.w;
            if constexpr (HAS_B) {
                const float4 mb = *reinterpret_cast<const float4*>(&s_mb[r][k]);
                a += mb.x * wlb.x + mb.y * wlb.y + mb.z * wlb.z + mb.w * wlb.w;
                a += xr.x * wrb.x + xr.y * wrb.y + xr.z * wrb.z + xr.w * wrb.w;
            }
            acc[r] = a;
        }
    }

    for (int r = 0; r < ROWS; ++r) {
        int i = row0 + r;
        if (i < n_dst) out[(size_t)i * D + j] = fmaxf(acc[r], 0.f);
    }
}

extern "C" void kernel_launch(void* const* d_in, const int* in_sizes, int n_in,
                              void* d_out, int out_size, void* d_ws, size_t ws_size,
                              hipStream_t stream) {
    const float* x_job = (const float*)d_in[0];
    const float* x_st  = (const float*)d_in[1];
    const float* x_mc  = (const float*)d_in[2];
    const float* x_rb  = (const float*)d_in[3];

    const int N_ST = 10000, N_MC = 10000, N_RB = 5000, E = 500000;
    const int ndst[NREL] = {N_ST, N_ST, N_MC, N_MC, N_RB};
    const int TOTAL_NODES = N_ST + N_ST + N_MC + N_MC + N_RB;  // 45000

    RelIdx ri;
    const float* Wl[NREL]; const float* bl[NREL]; const float* Wr[NREL];
    for (int r = 0; r < NREL; ++r) {
        ri.src[r] = (const int*)  d_in[4 + r * 5 + 0];
        ri.dst[r] = (const int*)  d_in[4 + r * 5 + 1];
        Wl[r]     = (const float*)d_in[4 + r * 5 + 2];
        bl[r]     = (const float*)d_in[4 + r * 5 + 3];
        Wr[r]     = (const float*)d_in[4 + r * 5 + 4];
    }

    // ---- workspace layout (4-byte units), total ~20.6 MB ----
    int* wsi = (int*)d_ws;
    float* wsf = (float*)d_ws;
    size_t off = 0;
    CsrPtrs cp;
    for (int r = 0; r < NREL; ++r) { cp.csr[r] = wsi + off; off += E; }
    size_t hist_off = off;
    for (int r = 0; r < NREL; ++r) { cp.rp[r]  = wsi + off; off += ndst[r] + 1; }
    size_t hist_len = off - hist_off;
    for (int r = 0; r < NREL; ++r) { cp.cur[r] = wsi + off; off += ndst[r]; }
    float* mean_st_b = wsf + off; off += (size_t)N_ST * D;
    float* mean_mc_b = wsf + off; off += (size_t)N_MC * D;

    float* out = (float*)d_out;
    GatherPtrs gp;
    for (int r = 0; r < NREL; ++r) { gp.csr[r] = cp.csr[r]; gp.rp[r] = cp.rp[r]; }
    gp.mean[0] = out;                           // st, rel a  (staged in d_out)
    gp.mean[1] = mean_st_b;                     // st, rel b
    gp.mean[2] = out + (size_t)N_ST * D;        // mc, rel a  (staged in d_out)
    gp.mean[3] = mean_mc_b;                     // mc, rel b
    gp.mean[4] = out + (size_t)(N_ST + N_MC) * D; // rb      (staged in d_out)

    ScanArgs sa;
    for (int r = 0; r < NREL; ++r) sa.n[r] = ndst[r];

    // zero only the histogram region
    hipMemsetAsync(wsi + hist_off, 0, hist_len * sizeof(int), stream);

    const int eb = (E + 255) / 256;
    hist_kernel<<<eb, 256, 0, stream>>>(ri, cp, E);
    scan_kernel<<<NREL, 256, 0, stream>>>(cp, sa, E);
    fill_kernel<<<eb, 256, 0, stream>>>(ri, cp, E);
    gather_mean_kernel<<<(TOTAL_NODES + 3) / 4, 256, 0, stream>>>(gp, x_job, TOTAL_NODES);

    sage_out_kernel<true><<<(N_ST + 7) / 8, 128, 0, stream>>>(
        gp.mean[0], Wl[0], bl[0], Wr[0],
        gp.mean[1], Wl[1], bl[1], Wr[1],
        x_st, out, N_ST);
    sage_out_kernel<true><<<(N_MC + 7) / 8, 128, 0, stream>>>(
        gp.mean[2], Wl[2], bl[2], Wr[2],
        gp.mean[3], Wl[3], bl[3], Wr[3],
        x_mc, out + (size_t)N_ST * D, N_MC);
    sage_out_kernel<false><<<(N_RB + 7) / 8, 128, 0, stream>>>(
        gp.mean[4], Wl[4], bl[4], Wr[4],
        nullptr, nullptr, nullptr, nullptr,
        x_rb, out + (size_t)(N_ST + N_MC) * D, N_RB);
}

// Round 3
// 582.396 us; speedup vs baseline: 7.7513x; 1.0499x over previous
//
#include <hip/hip_runtime.h>

#define D 128
#define NREL 5

// ---- pointer bundles passed by value (kernarg) ----
struct RelIdx {
    const int* src[NREL];
    const int* dst[NREL];
};
struct CsrPtrs {
    int* csr[NREL];   // per-rel edge source list, grouped by dst (size E)
    int* rp [NREL];   // histogram -> row_ptr (size n_dst+1)
    int* cur[NREL];   // fill cursors (size n_dst)
};
struct GatherPtrs {
    const int* csr[NREL];
    const int* rp [NREL];
    float*     mean[NREL];
};
struct ScanArgs { int n[NREL]; };

// ---------------------------------------------------------------------------
// fp32 -> bf16 (RNE) pack of x_job, 4 elems/thread
// ---------------------------------------------------------------------------
__device__ __forceinline__ ushort f2bf(float f) {
    unsigned u = __float_as_uint(f);
    unsigned r = (u + 0x7FFFu + ((u >> 16) & 1u)) >> 16;
    return (ushort)r;
}

__global__ __launch_bounds__(256) void cvt_bf16_kernel(
    const float* __restrict__ x, ushort* __restrict__ y, int n4)
{
    int t = blockIdx.x * 256 + threadIdx.x;
    if (t >= n4) return;
    float4 v = reinterpret_cast<const float4*>(x)[t];
    ushort4 o;
    o.x = f2bf(v.x); o.y = f2bf(v.y); o.z = f2bf(v.z); o.w = f2bf(v.w);
    reinterpret_cast<ushort4*>(y)[t] = o;
}

// ---------------------------------------------------------------------------
// CSR build step 1: per-dst edge count. 4 edges/thread, int4 index loads.
// ---------------------------------------------------------------------------
__global__ __launch_bounds__(256) void hist_kernel(RelIdx idx, CsrPtrs p, int E) {
    int e0 = (blockIdx.x * 256 + threadIdx.x) * 4;
    if (e0 >= E) return;
    #pragma unroll
    for (int r = 0; r < NREL; ++r) {
        const int* dp = idx.dst[r];
        if (e0 + 4 <= E) {
            int4 d4 = *reinterpret_cast<const int4*>(dp + e0);
            atomicAdd(&p.rp[r][d4.x], 1);
            atomicAdd(&p.rp[r][d4.y], 1);
            atomicAdd(&p.rp[r][d4.z], 1);
            atomicAdd(&p.rp[r][d4.w], 1);
        } else {
            for (int e = e0; e < E; ++e) atomicAdd(&p.rp[r][dp[e]], 1);
        }
    }
}

// ---------------------------------------------------------------------------
// CSR build step 2: in-place exclusive scan of the histogram; seeds cursors.
// ---------------------------------------------------------------------------
__global__ __launch_bounds__(256) void scan_kernel(CsrPtrs p, ScanArgs a, int E) {
    int r = blockIdx.x;
    int n = a.n[r];
    int* h = p.rp[r];
    int* c = p.cur[r];
    int tid = threadIdx.x;
    int chunk = (n + 255) >> 8;
    int lo = tid * chunk, hi = min(lo + chunk, n);
    int sum = 0;
    for (int i = lo; i < hi; ++i) sum += h[i];
    __shared__ int s[256];
    s[tid] = sum;
    __syncthreads();
    for (int d = 1; d < 256; d <<= 1) {
        int v = (tid >= d) ? s[tid - d] : 0;
        __syncthreads();
        if (tid >= d) s[tid] += v;
        __syncthreads();
    }
    int run = s[tid] - sum;              // exclusive prefix of this chunk
    for (int i = lo; i < hi; ++i) { int v = h[i]; h[i] = run; c[i] = run; run += v; }
    if (tid == 0) h[n] = E;
}

// ---------------------------------------------------------------------------
// CSR build step 3: scatter edge source ids into dst-grouped slots.
// ---------------------------------------------------------------------------
__global__ __launch_bounds__(256) void fill_kernel(RelIdx idx, CsrPtrs p, int E) {
    int e0 = (blockIdx.x * 256 + threadIdx.x) * 4;
    if (e0 >= E) return;
    #pragma unroll
    for (int r = 0; r < NREL; ++r) {
        const int* dp = idx.dst[r];
        const int* sp = idx.src[r];
        if (e0 + 4 <= E) {
            int4 d4 = *reinterpret_cast<const int4*>(dp + e0);
            int4 s4 = *reinterpret_cast<const int4*>(sp + e0);
            int p0 = atomicAdd(&p.cur[r][d4.x], 1); p.csr[r][p0] = s4.x;
            int p1 = atomicAdd(&p.cur[r][d4.y], 1); p.csr[r][p1] = s4.y;
            int p2 = atomicAdd(&p.cur[r][d4.z], 1); p.csr[r][p2] = s4.z;
            int p3 = atomicAdd(&p.cur[r][d4.w], 1); p.csr[r][p3] = s4.w;
        } else {
            for (int e = e0; e < E; ++e) {
                int pos = atomicAdd(&p.cur[r][dp[e]], 1);
                p.csr[r][pos] = sp[e];
            }
        }
    }
}

// ---------------------------------------------------------------------------
// Node -> (rel, idx) mapping for the gather kernels
// ---------------------------------------------------------------------------
__device__ __forceinline__ void node_map(int w, int& r, int& i) {
    if      (w < 10000) { r = 0; i = w; }
    else if (w < 20000) { r = 1; i = w - 10000; }
    else if (w < 30000) { r = 2; i = w - 20000; }
    else if (w < 40000) { r = 3; i = w - 30000; }
    else                { r = 4; i = w - 40000; }
}

// ---------------------------------------------------------------------------
// Gather-reduce (bf16 rows): one wave per dst node, lane owns 2 columns
// (one dword). 256B per row = 2 cache lines per edge. fp32 accumulation.
// ---------------------------------------------------------------------------
__global__ __launch_bounds__(256) void gather_mean_bf16_kernel(
    GatherPtrs g, const ushort* __restrict__ xb, int total_nodes)
{
    int w = blockIdx.x * 4 + (threadIdx.x >> 6);
    int lane = threadIdx.x & 63;
    if (w >= total_nodes) return;
    int r, i;
    node_map(w, r, i);
    const int* csr = g.csr[r];
    int start = g.rp[r][i], end = g.rp[r][i + 1];
    const ushort* base = xb + lane * 2;
    float ax = 0.f, ay = 0.f;
    int k = start;
    for (; k + 4 <= end; k += 4) {
        int s0 = csr[k], s1 = csr[k + 1], s2 = csr[k + 2], s3 = csr[k + 3];
        unsigned u0 = *reinterpret_cast<const unsigned*>(base + s0 * D);
        unsigned u1 = *reinterpret_cast<const unsigned*>(base + s1 * D);
        unsigned u2 = *reinterpret_cast<const unsigned*>(base + s2 * D);
        unsigned u3 = *reinterpret_cast<const unsigned*>(base + s3 * D);
        ax += __uint_as_float(u0 << 16) + __uint_as_float(u1 << 16)
            + __uint_as_float(u2 << 16) + __uint_as_float(u3 << 16);
        ay += __uint_as_float(u0 & 0xffff0000u) + __uint_as_float(u1 & 0xffff0000u)
            + __uint_as_float(u2 & 0xffff0000u) + __uint_as_float(u3 & 0xffff0000u);
    }
    for (; k < end; ++k) {
        unsigned u = *reinterpret_cast<const unsigned*>(base + csr[k] * D);
        ax += __uint_as_float(u << 16);
        ay += __uint_as_float(u & 0xffff0000u);
    }
    float inv = 1.0f / (float)max(end - start, 1);
    float2 m; m.x = ax * inv; m.y = ay * inv;
    *reinterpret_cast<float2*>(g.mean[r] + (size_t)i * D + lane * 2) = m;
}

// ---------------------------------------------------------------------------
// Gather-reduce (fp32 rows) — fallback when ws is too small for the bf16 copy
// ---------------------------------------------------------------------------
__global__ __launch_bounds__(256) void gather_mean_kernel(
    GatherPtrs g, const float* __restrict__ x_job, int total_nodes)
{
    int w = blockIdx.x * 4 + (threadIdx.x >> 6);
    int lane = threadIdx.x & 63;
    if (w >= total_nodes) return;
    int r, i;
    node_map(w, r, i);
    const int* csr = g.csr[r];
    int start = g.rp[r][i], end = g.rp[r][i + 1];
    const float* base = x_job + lane * 2;
    float ax = 0.f, ay = 0.f;
    int k = start;
    for (; k + 4 <= end; k += 4) {
        int s0 = csr[k], s1 = csr[k + 1], s2 = csr[k + 2], s3 = csr[k + 3];
        float2 v0 = *reinterpret_cast<const float2*>(base + s0 * D);
        float2 v1 = *reinterpret_cast<const float2*>(base + s1 * D);
        float2 v2 = *reinterpret_cast<const float2*>(base + s2 * D);
        float2 v3 = *reinterpret_cast<const float2*>(base + s3 * D);
        ax += v0.x + v1.x + v2.x + v3.x;
        ay += v0.y + v1.y + v2.y + v3.y;
    }
    for (; k < end; ++k) {
        float2 v = *reinterpret_cast<const float2*>(base + csr[k] * D);
        ax += v.x; ay += v.y;
    }
    float inv = 1.0f / (float)max(end - start, 1);
    float2 m; m.x = ax * inv; m.y = ay * inv;
    *reinterpret_cast<float2*>(g.mean[r] + (size_t)i * D + lane * 2) = m;
}

// ---------------------------------------------------------------------------
// Fused epilogue over all 3 dst types:
// out[i][j] = relu( sum_rel( mean_rel[i]·Wl_rel[j] + bl_rel[j]
//                            + x_dst[i]·Wr_rel[j] ) )
// mean_a may alias `out` (each block stages its rows to LDS before writing).
// ---------------------------------------------------------------------------
struct SageArgs {
    const float* mean_a[3]; const float* mean_b[3];
    const float* Wl_a[3]; const float* bl_a[3]; const float* Wr_a[3];
    const float* Wl_b[3]; const float* bl_b[3]; const float* Wr_b[3];
    const float* x[3]; float* out[3];
    int n[3]; int blk_start[3];
};

__global__ __launch_bounds__(128) void sage_out_fused_kernel(SageArgs A) {
    constexpr int ROWS = 8;
    __shared__ float s_ma[ROWS][D];
    __shared__ float s_x [ROWS][D];
    __shared__ float s_mb[ROWS][D];

    int b = blockIdx.x;
    int ty = (b >= A.blk_start[1]) + (b >= A.blk_start[2]);
    int rb = b - A.blk_start[ty];
    const int n_dst = A.n[ty];
    const bool has_b = (A.mean_b[ty] != nullptr);

    const float* mean_a = A.mean_a[ty];
    const float* mean_b = A.mean_b[ty];
    const float* x_dst  = A.x[ty];
    float* out          = A.out[ty];

    const int j = threadIdx.x;
    const int row0 = rb * ROWS;

    for (int r = 0; r < ROWS; ++r) {
        int i = row0 + r;
        if (i < n_dst) {
            s_ma[r][j] = mean_a[(size_t)i * D + j];
            s_x [r][j] = x_dst [(size_t)i * D + j];
            s_mb[r][j] = has_b ? mean_b[(size_t)i * D + j] : 0.f;
        } else {
            s_ma[r][j] = 0.f;
            s_x [r][j] = 0.f;
            s_mb[r][j] = 0.f;
        }
    }
    __syncthreads();

    float bias = A.bl_a[ty][j];
    if (has_b) bias += A.bl_b[ty][j];

    float acc[ROWS];
    #pragma unroll
    for (int r = 0; r < ROWS; ++r) acc[r] = bias;

    const float* Wl_a = A.Wl_a[ty];
    const float* Wr_a = A.Wr_a[ty];

    if (has_b) {
        const float* Wl_b = A.Wl_b[ty];
        const float* Wr_b = A.Wr_b[ty];
        for (int k = 0; k < D; k += 4) {
            const float4 wla = *reinterpret_cast<const float4*>(Wl_a + (size_t)j * D + k);
            const float4 wra = *reinterpret_cast<const float4*>(Wr_a + (size_t)j * D + k);
            const float4 wlb = *reinterpret_cast<const float4*>(Wl_b + (size_t)j * D + k);
            const float4 wrb = *reinterpret_cast<const float4*>(Wr_b + (size_t)j * D + k);
            #pragma unroll
            for (int r = 0; r < ROWS; ++r) {
                const float4 ma = *reinterpret_cast<const float4*>(&s_ma[r][k]);
                const float4 mb = *reinterpret_cast<const float4*>(&s_mb[r][k]);
                const float4 xr = *reinterpret_cast<const float4*>(&s_x [r][k]);
                float a = acc[r];
                a += ma.x * wla.x + ma.y * wla.y + ma.z * wla.z + ma.w * wla.w;
                a += xr.x * wra.x + xr.y * wra.y + xr.z * wra.z + xr.w * wra.w;
                a += mb.x * wlb.x + mb.y * wlb.y + mb.z * wlb.z + mb.w * wlb.w;
                a += xr.x * wrb.x + xr.y * wrb.y + xr.z * wrb.z + xr.w * wrb.w;
                acc[r] = a;
            }
        }
    } else {
        for (int k = 0; k < D; k += 4) {
            const float4 wla = *reinterpret_cast<const float4*>(Wl_a + (size_t)j * D + k);
            const float4 wra = *reinterpret_cast<const float4*>(Wr_a + (size_t)j * D + k);
            #pragma unroll
            for (int r = 0; r < ROWS; ++r) {
                const float4 ma = *reinterpret_cast<const float4*>(&s_ma[r][k]);
                const float4 xr = *reinterpret_cast<const float4*>(&s_x [r][k]);
                float a = acc[r];
                a += ma.x * wla.x + ma.y * wla.y + ma.z * wla.z + ma.w * wla.w;
                a += xr.x * wra.x + xr.y * wra.y + xr.z * wra.z + xr.w * wra.w;
                acc[r] = a;
            }
        }
    }

    for (int r = 0; r < ROWS; ++r) {
        int i = row0 + r;
        if (i < n_dst) out[(size_t)i * D + j] = fmaxf(acc[r], 0.f);
    }
}

extern "C" void kernel_launch(void* const* d_in, const int* in_sizes, int n_in,
                              void* d_out, int out_size, void* d_ws, size_t ws_size,
                              hipStream_t stream) {
    const float* x_job = (const float*)d_in[0];
    const float* x_st  = (const float*)d_in[1];
    const float* x_mc  = (const float*)d_in[2];
    const float* x_rb  = (const float*)d_in[3];

    const int N_JOB = 100000, N_ST = 10000, N_MC = 10000, N_RB = 5000, E = 500000;
    const int ndst[NREL] = {N_ST, N_ST, N_MC, N_MC, N_RB};
    const int TOTAL_NODES = N_ST + N_ST + N_MC + N_MC + N_RB;  // 45000

    RelIdx ri;
    const float* Wl[NREL]; const float* bl[NREL]; const float* Wr[NREL];
    for (int r = 0; r < NREL; ++r) {
        ri.src[r] = (const int*)  d_in[4 + r * 5 + 0];
        ri.dst[r] = (const int*)  d_in[4 + r * 5 + 1];
        Wl[r]     = (const float*)d_in[4 + r * 5 + 2];
        bl[r]     = (const float*)d_in[4 + r * 5 + 3];
        Wr[r]     = (const float*)d_in[4 + r * 5 + 4];
    }

    // ---- workspace layout (4-byte units) ----
    int* wsi = (int*)d_ws;
    float* wsf = (float*)d_ws;
    size_t off = 0;
    CsrPtrs cp;
    for (int r = 0; r < NREL; ++r) { cp.csr[r] = wsi + off; off += E; }
    size_t hist_off = off;
    for (int r = 0; r < NREL; ++r) { cp.rp[r]  = wsi + off; off += ndst[r] + 1; }
    size_t hist_len = off - hist_off;
    for (int r = 0; r < NREL; ++r) { cp.cur[r] = wsi + off; off += ndst[r]; }
    float* mean_st_b = wsf + off; off += (size_t)N_ST * D;
    float* mean_mc_b = wsf + off; off += (size_t)N_MC * D;
    ushort* x_bf = (ushort*)(wsi + off);
    size_t off_bf16 = off + (size_t)N_JOB * D / 2;   // bf16 copy: N_JOB*D ushorts
    const bool use_bf16 = (off_bf16 * sizeof(int) <= ws_size);

    float* out = (float*)d_out;
    GatherPtrs gp;
    for (int r = 0; r < NREL; ++r) { gp.csr[r] = cp.csr[r]; gp.rp[r] = cp.rp[r]; }
    gp.mean[0] = out;                             // st, rel a (staged in d_out)
    gp.mean[1] = mean_st_b;                       // st, rel b
    gp.mean[2] = out + (size_t)N_ST * D;          // mc, rel a (staged in d_out)
    gp.mean[3] = mean_mc_b;                       // mc, rel b
    gp.mean[4] = out + (size_t)(N_ST + N_MC) * D; // rb       (staged in d_out)

    ScanArgs sa;
    for (int r = 0; r < NREL; ++r) sa.n[r] = ndst[r];

    // zero only the histogram region
    hipMemsetAsync(wsi + hist_off, 0, hist_len * sizeof(int), stream);

    if (use_bf16) {
        int n4 = N_JOB * D / 4;
        cvt_bf16_kernel<<<(n4 + 255) / 256, 256, 0, stream>>>(x_job, x_bf, n4);
    }

    const int eb4 = (E / 4 + 255) / 256;
    hist_kernel<<<eb4, 256, 0, stream>>>(ri, cp, E);
    scan_kernel<<<NREL, 256, 0, stream>>>(cp, sa, E);
    fill_kernel<<<eb4, 256, 0, stream>>>(ri, cp, E);

    if (use_bf16)
        gather_mean_bf16_kernel<<<(TOTAL_NODES + 3) / 4, 256, 0, stream>>>(gp, x_bf, TOTAL_NODES);
    else
        gather_mean_kernel<<<(TOTAL_NODES + 3) / 4, 256, 0, stream>>>(gp, x_job, TOTAL_NODES);

    SageArgs A;
    // type 0: station (rels 0,1)   type 1: machine (rels 2,3)   type 2: robot (rel 4)
    A.mean_a[0] = gp.mean[0]; A.mean_b[0] = gp.mean[1];
    A.Wl_a[0] = Wl[0]; A.bl_a[0] = bl[0]; A.Wr_a[0] = Wr[0];
    A.Wl_b[0] = Wl[1]; A.bl_b[0] = bl[1]; A.Wr_b[0] = Wr[1];
    A.x[0] = x_st; A.out[0] = out; A.n[0] = N_ST;

    A.mean_a[1] = gp.mean[2]; A.mean_b[1] = gp.mean[3];
    A.Wl_a[1] = Wl[2]; A.bl_a[1] = bl[2]; A.Wr_a[1] = Wr[2];
    A.Wl_b[1] = Wl[3]; A.bl_b[1] = bl[3]; A.Wr_b[1] = Wr[3];
    A.x[1] = x_mc; A.out[1] = out + (size_t)N_ST * D; A.n[1] = N_MC;

    A.mean_a[2] = gp.mean[4]; A.mean_b[2] = nullptr;
    A.Wl_a[2] = Wl[4]; A.bl_a[2] = bl[4]; A.Wr_a[2] = Wr[4];
    A.Wl_b[2] = nullptr; A.bl_b[2] = nullptr; A.Wr_b[2] = nullptr;
    A.x[2] = x_rb; A.out[2] = out + (size_t)(N_ST + N_MC) * D; A.n[2] = N_RB;

    int nb0 = (N_ST + 7) / 8, nb1 = (N_MC + 7) / 8, nb2 = (N_RB + 7) / 8;
    A.blk_start[0] = 0;
    A.blk_start[1] = nb0;
    A.blk_start[2] = nb0 + nb1;

    sage_out_fused_kernel<<<nb0 + nb1 + nb2, 128, 0, stream>>>(A);
}

// Round 4
// 488.084 us; speedup vs baseline: 9.2491x; 1.1932x over previous
//
#include <hip/hip_runtime.h>

#define D 128
#define NREL 5

// ---- pointer bundles passed by value (kernarg) ----
struct RelIdx {
    const int* src[NREL];
    const int* dst[NREL];
};
struct CsrPtrs {
    int* csr[NREL];   // per-rel edge source list, grouped by dst (size E)
    int* rp [NREL];   // histogram -> row_ptr (size n_dst+1)
    int* cur[NREL];   // fill cursors (size n_dst)
};
struct GatherPtrs {
    const int* csr[NREL];
    const int* rp [NREL];
    float*     mean[NREL];
};
struct ScanArgs { int n[NREL]; };

// ---------------------------------------------------------------------------
// fp32 -> bf16 (RNE) pack of x_job, 4 elems/thread
// ---------------------------------------------------------------------------
__device__ __forceinline__ ushort f2bf(float f) {
    unsigned u = __float_as_uint(f);
    unsigned r = (u + 0x7FFFu + ((u >> 16) & 1u)) >> 16;
    return (ushort)r;
}

__global__ __launch_bounds__(256) void cvt_bf16_kernel(
    const float* __restrict__ x, ushort* __restrict__ y, int n4)
{
    int t = blockIdx.x * 256 + threadIdx.x;
    if (t >= n4) return;
    float4 v = reinterpret_cast<const float4*>(x)[t];
    ushort4 o;
    o.x = f2bf(v.x); o.y = f2bf(v.y); o.z = f2bf(v.z); o.w = f2bf(v.w);
    reinterpret_cast<ushort4*>(y)[t] = o;
}

// ---------------------------------------------------------------------------
// CSR build step 1: per-dst edge count. 4 edges/thread, int4 index loads.
// ---------------------------------------------------------------------------
__global__ __launch_bounds__(256) void hist_kernel(RelIdx idx, CsrPtrs p, int E) {
    int e0 = (blockIdx.x * 256 + threadIdx.x) * 4;
    if (e0 >= E) return;
    #pragma unroll
    for (int r = 0; r < NREL; ++r) {
        const int* dp = idx.dst[r];
        if (e0 + 4 <= E) {
            int4 d4 = *reinterpret_cast<const int4*>(dp + e0);
            atomicAdd(&p.rp[r][d4.x], 1);
            atomicAdd(&p.rp[r][d4.y], 1);
            atomicAdd(&p.rp[r][d4.z], 1);
            atomicAdd(&p.rp[r][d4.w], 1);
        } else {
            for (int e = e0; e < E; ++e) atomicAdd(&p.rp[r][dp[e]], 1);
        }
    }
}

// ---------------------------------------------------------------------------
// CSR build step 2: in-place exclusive scan of the histogram; seeds cursors.
// ---------------------------------------------------------------------------
__global__ __launch_bounds__(256) void scan_kernel(CsrPtrs p, ScanArgs a, int E) {
    int r = blockIdx.x;
    int n = a.n[r];
    int* h = p.rp[r];
    int* c = p.cur[r];
    int tid = threadIdx.x;
    int chunk = (n + 255) >> 8;
    int lo = tid * chunk, hi = min(lo + chunk, n);
    int sum = 0;
    for (int i = lo; i < hi; ++i) sum += h[i];
    __shared__ int s[256];
    s[tid] = sum;
    __syncthreads();
    for (int d = 1; d < 256; d <<= 1) {
        int v = (tid >= d) ? s[tid - d] : 0;
        __syncthreads();
        if (tid >= d) s[tid] += v;
        __syncthreads();
    }
    int run = s[tid] - sum;              // exclusive prefix of this chunk
    for (int i = lo; i < hi; ++i) { int v = h[i]; h[i] = run; c[i] = run; run += v; }
    if (tid == 0) h[n] = E;
}

// ---------------------------------------------------------------------------
// CSR build step 3: scatter edge source ids into dst-grouped slots.
// ---------------------------------------------------------------------------
__global__ __launch_bounds__(256) void fill_kernel(RelIdx idx, CsrPtrs p, int E) {
    int e0 = (blockIdx.x * 256 + threadIdx.x) * 4;
    if (e0 >= E) return;
    #pragma unroll
    for (int r = 0; r < NREL; ++r) {
        const int* dp = idx.dst[r];
        const int* sp = idx.src[r];
        if (e0 + 4 <= E) {
            int4 d4 = *reinterpret_cast<const int4*>(dp + e0);
            int4 s4 = *reinterpret_cast<const int4*>(sp + e0);
            int p0 = atomicAdd(&p.cur[r][d4.x], 1); p.csr[r][p0] = s4.x;
            int p1 = atomicAdd(&p.cur[r][d4.y], 1); p.csr[r][p1] = s4.y;
            int p2 = atomicAdd(&p.cur[r][d4.z], 1); p.csr[r][p2] = s4.z;
            int p3 = atomicAdd(&p.cur[r][d4.w], 1); p.csr[r][p3] = s4.w;
        } else {
            for (int e = e0; e < E; ++e) {
                int pos = atomicAdd(&p.cur[r][dp[e]], 1);
                p.csr[r][pos] = sp[e];
            }
        }
    }
}

// ---------------------------------------------------------------------------
// Node -> (rel, idx) mapping for the gather kernels
// ---------------------------------------------------------------------------
__device__ __forceinline__ void node_map(int w, int& r, int& i) {
    if      (w < 10000) { r = 0; i = w; }
    else if (w < 20000) { r = 1; i = w - 10000; }
    else if (w < 30000) { r = 2; i = w - 20000; }
    else if (w < 40000) { r = 3; i = w - 30000; }
    else                { r = 4; i = w - 40000; }
}

// ---------------------------------------------------------------------------
// Gather-reduce (bf16 rows): one wave per dst node, lane owns 2 columns.
// ---------------------------------------------------------------------------
__global__ __launch_bounds__(256) void gather_mean_bf16_kernel(
    GatherPtrs g, const ushort* __restrict__ xb, int total_nodes)
{
    int w = blockIdx.x * 4 + (threadIdx.x >> 6);
    int lane = threadIdx.x & 63;
    if (w >= total_nodes) return;
    int r, i;
    node_map(w, r, i);
    const int* csr = g.csr[r];
    int start = g.rp[r][i], end = g.rp[r][i + 1];
    const ushort* base = xb + lane * 2;
    float ax = 0.f, ay = 0.f;
    int k = start;
    for (; k + 4 <= end; k += 4) {
        int s0 = csr[k], s1 = csr[k + 1], s2 = csr[k + 2], s3 = csr[k + 3];
        unsigned u0 = *reinterpret_cast<const unsigned*>(base + s0 * D);
        unsigned u1 = *reinterpret_cast<const unsigned*>(base + s1 * D);
        unsigned u2 = *reinterpret_cast<const unsigned*>(base + s2 * D);
        unsigned u3 = *reinterpret_cast<const unsigned*>(base + s3 * D);
        ax += __uint_as_float(u0 << 16) + __uint_as_float(u1 << 16)
            + __uint_as_float(u2 << 16) + __uint_as_float(u3 << 16);
        ay += __uint_as_float(u0 & 0xffff0000u) + __uint_as_float(u1 & 0xffff0000u)
            + __uint_as_float(u2 & 0xffff0000u) + __uint_as_float(u3 & 0xffff0000u);
    }
    for (; k < end; ++k) {
        unsigned u = *reinterpret_cast<const unsigned*>(base + csr[k] * D);
        ax += __uint_as_float(u << 16);
        ay += __uint_as_float(u & 0xffff0000u);
    }
    float inv = 1.0f / (float)max(end - start, 1);
    float2 m; m.x = ax * inv; m.y = ay * inv;
    *reinterpret_cast<float2*>(g.mean[r] + (size_t)i * D + lane * 2) = m;
}

// ---------------------------------------------------------------------------
// Gather-reduce (fp32 rows) — fallback when ws is too small for the bf16 copy
// ---------------------------------------------------------------------------
__global__ __launch_bounds__(256) void gather_mean_kernel(
    GatherPtrs g, const float* __restrict__ x_job, int total_nodes)
{
    int w = blockIdx.x * 4 + (threadIdx.x >> 6);
    int lane = threadIdx.x & 63;
    if (w >= total_nodes) return;
    int r, i;
    node_map(w, r, i);
    const int* csr = g.csr[r];
    int start = g.rp[r][i], end = g.rp[r][i + 1];
    const float* base = x_job + lane * 2;
    float ax = 0.f, ay = 0.f;
    int k = start;
    for (; k + 4 <= end; k += 4) {
        int s0 = csr[k], s1 = csr[k + 1], s2 = csr[k + 2], s3 = csr[k + 3];
        float2 v0 = *reinterpret_cast<const float2*>(base + s0 * D);
        float2 v1 = *reinterpret_cast<const float2*>(base + s1 * D);
        float2 v2 = *reinterpret_cast<const float2*>(base + s2 * D);
        float2 v3 = *reinterpret_cast<const float2*>(base + s3 * D);
        ax += v0.x + v1.x + v2.x + v3.x;
        ay += v0.y + v1.y + v2.y + v3.y;
    }
    for (; k < end; ++k) {
        float2 v = *reinterpret_cast<const float2*>(base + csr[k] * D);
        ax += v.x; ay += v.y;
    }
    float inv = 1.0f / (float)max(end - start, 1);
    float2 m; m.x = ax * inv; m.y = ay * inv;
    *reinterpret_cast<float2*>(g.mean[r] + (size_t)i * D + lane * 2) = m;
}

// ---------------------------------------------------------------------------
// prep: build per-type B matrices [K][128] (transposed, Wr pre-summed) and
// bias sums.  t0/t1: K=384 (Wl_a^T | Wl_b^T | (Wr_a+Wr_b)^T).  t2: K=256.
// j-fastest layout -> coalesced writes; W reads are L2-resident (640 KB).
// ---------------------------------------------------------------------------
struct PrepArgs {
    const float* Wl[NREL]; const float* Wr[NREL]; const float* bl[NREL];
    float* B0; float* B1; float* B2; float* bias;  // bias: 3*128
};

__global__ __launch_bounds__(256) void prep_b_kernel(PrepArgs P) {
    int idx = blockIdx.x * 256 + threadIdx.x;
    if (idx < 49152) {                       // B0: 384x128
        int k = idx >> 7, j = idx & 127;
        float v;
        if (k < 128)      v = P.Wl[0][j * D + k];
        else if (k < 256) v = P.Wl[1][j * D + (k - 128)];
        else              v = P.Wr[0][j * D + (k - 256)] + P.Wr[1][j * D + (k - 256)];
        P.B0[idx] = v;
    } else if (idx < 98304) {                // B1: 384x128
        int l = idx - 49152;
        int k = l >> 7, j = l & 127;
        float v;
        if (k < 128)      v = P.Wl[2][j * D + k];
        else if (k < 256) v = P.Wl[3][j * D + (k - 128)];
        else              v = P.Wr[2][j * D + (k - 256)] + P.Wr[3][j * D + (k - 256)];
        P.B1[l] = v;
    } else if (idx < 131072) {               // B2: 256x128
        int l = idx - 98304;
        int k = l >> 7, j = l & 127;
        float v = (k < 128) ? P.Wl[4][j * D + k] : P.Wr[4][j * D + (k - 128)];
        P.B2[l] = v;
    } else if (idx < 131456) {               // bias: 3 x 128
        int l = idx - 131072;
        int t = l >> 7, j = l & 127;
        float v = (t == 0) ? P.bl[0][j] + P.bl[1][j]
                : (t == 1) ? P.bl[2][j] + P.bl[3][j]
                           : P.bl[4][j];
        P.bias[l] = v;
    }
}

// ---------------------------------------------------------------------------
// Register-tiled fp32 GEMM epilogue: out = relu(A·B + bias).
// A = [mean_a | mean_b | x] per type (virtual concat via Asrc[seg]).
// Block: 128 threads, tile 64x128, BK=32, per-thread 8x8 accumulator.
// mean_a may alias out: each block reads only rows it later writes.
// ---------------------------------------------------------------------------
struct GemmArgs {
    const float* Asrc[3][3];   // [type][k-segment of 128]
    const float* B[3];
    const float* bias[3];      // summed
    float* out[3];
    int M[3]; int K[3]; int blk_start[3];
};

__global__ __launch_bounds__(128) void sage_gemm_kernel(GemmArgs A) {
    __shared__ float sA[64][40];    // pad 32->40: conflict-free, 16B-aligned rows
    __shared__ float sB[32][128];

    int b = blockIdx.x;
    int ty_ = (b >= A.blk_start[1]) + (b >= A.blk_start[2]);
    int mb = b - A.blk_start[ty_];
    const int M = A.M[ty_];
    const int K = A.K[ty_];
    const int row0 = mb * 64;
    const float* Bmat = A.B[ty_];

    const int tid = threadIdx.x;
    const int txc = tid & 15;    // col group: cols txc*8 .. +7
    const int tyr = tid >> 4;    // row group: rows tyr + 8*m, m in [0,8)

    float acc[8][8];
    #pragma unroll
    for (int m = 0; m < 8; ++m)
        #pragma unroll
        for (int n = 0; n < 8; ++n) acc[m][n] = 0.f;

    for (int kc = 0; kc < K; kc += 32) {
        if (kc) __syncthreads();
        const float* src = A.Asrc[ty_][kc >> 7];
        const int c0 = kc & 127;

        // stage A: 64 rows x 32 cols = 512 float4, 4 per thread
        #pragma unroll
        for (int p = 0; p < 4; ++p) {
            int flat = p * 128 + tid;
            int r = flat >> 3, c4 = (flat & 7) * 4;
            int grow = row0 + r; if (grow >= M) grow = M - 1;
            float4 v = *reinterpret_cast<const float4*>(src + (size_t)grow * D + c0 + c4);
            *reinterpret_cast<float4*>(&sA[r][c4]) = v;
        }
        // stage B: 32 rows x 128 cols = 1024 float4, 8 per thread
        #pragma unroll
        for (int p = 0; p < 8; ++p) {
            int f4 = p * 128 + tid;
            int k = f4 >> 5, c4 = (f4 & 31) * 4;
            float4 v = *reinterpret_cast<const float4*>(Bmat + (size_t)(kc + k) * D + c4);
            *reinterpret_cast<float4*>(&sB[k][c4]) = v;
        }
        __syncthreads();

        #pragma unroll
        for (int kk = 0; kk < 32; kk += 4) {
            float4 av[8];
            #pragma unroll
            for (int m = 0; m < 8; ++m)
                av[m] = *reinterpret_cast<const float4*>(&sA[tyr + 8 * m][kk]);
            #pragma unroll
            for (int t = 0; t < 4; ++t) {
                float4 b0 = *reinterpret_cast<const float4*>(&sB[kk + t][txc * 8]);
                float4 b1 = *reinterpret_cast<const float4*>(&sB[kk + t][txc * 8 + 4]);
                #pragma unroll
                for (int m = 0; m < 8; ++m) {
                    float am = (t == 0) ? av[m].x : (t == 1) ? av[m].y
                             : (t == 2) ? av[m].z : av[m].w;
                    acc[m][0] += am * b0.x; acc[m][1] += am * b0.y;
                    acc[m][2] += am * b0.z; acc[m][3] += am * b0.w;
                    acc[m][4] += am * b1.x; acc[m][5] += am * b1.y;
                    acc[m][6] += am * b1.z; acc[m][7] += am * b1.w;
                }
            }
        }
    }

    const float* bias = A.bias[ty_];
    float bv[8];
    #pragma unroll
    for (int n = 0; n < 8; ++n) bv[n] = bias[txc * 8 + n];

    float* out = A.out[ty_];
    #pragma unroll
    for (int m = 0; m < 8; ++m) {
        int grow = row0 + tyr + 8 * m;
        if (grow < M) {
            float4 o0, o1;
            o0.x = fmaxf(acc[m][0] + bv[0], 0.f);
            o0.y = fmaxf(acc[m][1] + bv[1], 0.f);
            o0.z = fmaxf(acc[m][2] + bv[2], 0.f);
            o0.w = fmaxf(acc[m][3] + bv[3], 0.f);
            o1.x = fmaxf(acc[m][4] + bv[4], 0.f);
            o1.y = fmaxf(acc[m][5] + bv[5], 0.f);
            o1.z = fmaxf(acc[m][6] + bv[6], 0.f);
            o1.w = fmaxf(acc[m][7] + bv[7], 0.f);
            *reinterpret_cast<float4*>(out + (size_t)grow * D + txc * 8) = o0;
            *reinterpret_cast<float4*>(out + (size_t)grow * D + txc * 8 + 4) = o1;
        }
    }
}

extern "C" void kernel_launch(void* const* d_in, const int* in_sizes, int n_in,
                              void* d_out, int out_size, void* d_ws, size_t ws_size,
                              hipStream_t stream) {
    const float* x_job = (const float*)d_in[0];
    const float* x_st  = (const float*)d_in[1];
    const float* x_mc  = (const float*)d_in[2];
    const float* x_rb  = (const float*)d_in[3];

    const int N_JOB = 100000, N_ST = 10000, N_MC = 10000, N_RB = 5000, E = 500000;
    const int ndst[NREL] = {N_ST, N_ST, N_MC, N_MC, N_RB};
    const int TOTAL_NODES = N_ST + N_ST + N_MC + N_MC + N_RB;  // 45000

    RelIdx ri;
    const float* Wl[NREL]; const float* bl[NREL]; const float* Wr[NREL];
    for (int r = 0; r < NREL; ++r) {
        ri.src[r] = (const int*)  d_in[4 + r * 5 + 0];
        ri.dst[r] = (const int*)  d_in[4 + r * 5 + 1];
        Wl[r]     = (const float*)d_in[4 + r * 5 + 2];
        bl[r]     = (const float*)d_in[4 + r * 5 + 3];
        Wr[r]     = (const float*)d_in[4 + r * 5 + 4];
    }

    // ---- workspace layout (4-byte units) ----
    int* wsi = (int*)d_ws;
    float* wsf = (float*)d_ws;
    size_t off = 0;
    CsrPtrs cp;
    for (int r = 0; r < NREL; ++r) { cp.csr[r] = wsi + off; off += E; }
    size_t hist_off = off;
    for (int r = 0; r < NREL; ++r) { cp.rp[r]  = wsi + off; off += ndst[r] + 1; }
    size_t hist_len = off - hist_off;
    for (int r = 0; r < NREL; ++r) { cp.cur[r] = wsi + off; off += ndst[r]; }
    float* mean_st_b = wsf + off; off += (size_t)N_ST * D;
    float* mean_mc_b = wsf + off; off += (size_t)N_MC * D;
    float* B0   = wsf + off; off += 384 * 128;
    float* B1   = wsf + off; off += 384 * 128;
    float* B2   = wsf + off; off += 256 * 128;
    float* bsum = wsf + off; off += 3 * 128;
    ushort* x_bf = (ushort*)(wsi + off);
    size_t off_bf16 = off + (size_t)N_JOB * D / 2;
    const bool use_bf16 = (off_bf16 * sizeof(int) <= ws_size);

    float* out = (float*)d_out;
    GatherPtrs gp;
    for (int r = 0; r < NREL; ++r) { gp.csr[r] = cp.csr[r]; gp.rp[r] = cp.rp[r]; }
    gp.mean[0] = out;                             // st, rel a (staged in d_out)
    gp.mean[1] = mean_st_b;                       // st, rel b
    gp.mean[2] = out + (size_t)N_ST * D;          // mc, rel a (staged in d_out)
    gp.mean[3] = mean_mc_b;                       // mc, rel b
    gp.mean[4] = out + (size_t)(N_ST + N_MC) * D; // rb       (staged in d_out)

    ScanArgs sa;
    for (int r = 0; r < NREL; ++r) sa.n[r] = ndst[r];

    hipMemsetAsync(wsi + hist_off, 0, hist_len * sizeof(int), stream);

    if (use_bf16) {
        int n4 = N_JOB * D / 4;
        cvt_bf16_kernel<<<(n4 + 255) / 256, 256, 0, stream>>>(x_job, x_bf, n4);
    }

    const int eb4 = (E / 4 + 255) / 256;
    hist_kernel<<<eb4, 256, 0, stream>>>(ri, cp, E);
    scan_kernel<<<NREL, 256, 0, stream>>>(cp, sa, E);
    fill_kernel<<<eb4, 256, 0, stream>>>(ri, cp, E);

    if (use_bf16)
        gather_mean_bf16_kernel<<<(TOTAL_NODES + 3) / 4, 256, 0, stream>>>(gp, x_bf, TOTAL_NODES);
    else
        gather_mean_kernel<<<(TOTAL_NODES + 3) / 4, 256, 0, stream>>>(gp, x_job, TOTAL_NODES);

    PrepArgs P;
    for (int r = 0; r < NREL; ++r) { P.Wl[r] = Wl[r]; P.Wr[r] = Wr[r]; P.bl[r] = bl[r]; }
    P.B0 = B0; P.B1 = B1; P.B2 = B2; P.bias = bsum;
    prep_b_kernel<<<(131456 + 255) / 256, 256, 0, stream>>>(P);

    GemmArgs GA;
    GA.Asrc[0][0] = gp.mean[0]; GA.Asrc[0][1] = gp.mean[1]; GA.Asrc[0][2] = x_st;
    GA.Asrc[1][0] = gp.mean[2]; GA.Asrc[1][1] = gp.mean[3]; GA.Asrc[1][2] = x_mc;
    GA.Asrc[2][0] = gp.mean[4]; GA.Asrc[2][1] = x_rb;       GA.Asrc[2][2] = x_rb;
    GA.B[0] = B0; GA.B[1] = B1; GA.B[2] = B2;
    GA.bias[0] = bsum; GA.bias[1] = bsum + 128; GA.bias[2] = bsum + 256;
    GA.out[0] = out;
    GA.out[1] = out + (size_t)N_ST * D;
    GA.out[2] = out + (size_t)(N_ST + N_MC) * D;
    GA.M[0] = N_ST; GA.M[1] = N_MC; GA.M[2] = N_RB;
    GA.K[0] = 384;  GA.K[1] = 384;  GA.K[2] = 256;
    int nb0 = (N_ST + 63) / 64, nb1 = (N_MC + 63) / 64, nb2 = (N_RB + 63) / 64;
    GA.blk_start[0] = 0;
    GA.blk_start[1] = nb0;
    GA.blk_start[2] = nb0 + nb1;

    sage_gemm_kernel<<<nb0 + nb1 + nb2, 128, 0, stream>>>(GA);
}